// Round 12
// baseline (123.571 us; speedup 1.0000x reference)
//
#include <hip/hip_runtime.h>
#include <hip/hip_fp16.h>
#include <math.h>

#define B_  32
#define H0  512
#define W0  512
#define Hh  255
#define Wh  255
#define HP  259   // padded: rows/cols 0,1 zero; 2..256 = data y=0..254; 257,258 zero

typedef __attribute__((ext_vector_type(8))) _Float16 f16x8;
typedef __attribute__((ext_vector_type(4))) float    f32x4;
typedef __attribute__((ext_vector_type(4))) unsigned int u32x4;

static __device__ __forceinline__ __half2 u2h2(unsigned int u) {
    __half2 h; __builtin_memcpy(&h, &u, 4); return h;
}
static __device__ __forceinline__ unsigned int h2u(__half2 h) {
    unsigned int u; __builtin_memcpy(&u, &h, 4); return u;
}

// ---------------- Kernel A: conv1+ReLU+maxpool -> padded f16x4 h; ring blocks zero the pad ----------------
// (R9-proven version, unchanged)
__global__ __launch_bounds__(256) void conv_pool_kernel(
    const float* __restrict__ x,      // [B,1,512,512]
    const float* __restrict__ w,      // [3,1,3,3]
    const float* __restrict__ bias,   // [3]
    uint2* __restrict__ hp)           // [B][259][259] of 4xf16 (c0,c1,c2,0)
{
    const int b = blockIdx.z;
    const int tx = threadIdx.x, ty = threadIdx.y;
    const int tid = ty * 16 + tx;

    if (blockIdx.y == 16) {           // ---- pad-ring zeroing (16 blocks/image) ----
        uint2* hpb = hp + b * (HP * HP);
        const int gid = blockIdx.x * 256 + tid;
        if (gid < 2072) {
            int r, c;
            if (gid < 1036) {                      // row strips 0,1,257,258
                int rr = gid / 259; c = gid - rr * 259;
                r = rr + (rr >= 2 ? 255 : 0);
            } else {                               // col strips 0,1,257,258
                int u = gid - 1036;
                int cc = u / 259; r = u - cc * 259;
                c = cc + (cc >= 2 ? 255 : 0);
            }
            hpb[r * HP + c] = make_uint2(0u, 0u);
        }
        return;
    }

    __shared__ float sx[35][36];
    __shared__ float sc[33 * 100];    // conv values [r][c*3+ch]; lane stride 6 dwords -> conflict-free
    const int i0 = blockIdx.y * 16;
    const int j0 = blockIdx.x * 16;

    const float* xb = x + b * (H0 * W0);
    for (int t = tid; t < 35 * 35; t += 256) {
        int r = t / 35, c = t - r * 35;
        int gr = 2 * i0 - 1 + r;
        int gc = 2 * j0 - 1 + c;
        float v = 0.f;
        if ((unsigned)gr < (unsigned)H0 && (unsigned)gc < (unsigned)W0) v = xb[gr * W0 + gc];
        sx[r][c] = v;
    }
    __syncthreads();

    float w0[9], w1[9], w2[9];
#pragma unroll
    for (int t = 0; t < 9; ++t) { w0[t] = w[t]; w1[t] = w[9 + t]; w2[t] = w[18 + t]; }
    const float b0 = bias[0], b1 = bias[1], b2 = bias[2];

    for (int t = tid; t < 33 * 33; t += 256) {
        int r = t / 33, c = t - r * 33;
        float s0 = b0, s1 = b1, s2 = b2;
#pragma unroll
        for (int ky = 0; ky < 3; ++ky) {
#pragma unroll
            for (int kx = 0; kx < 3; ++kx) {
                float v = sx[r + ky][c + kx];
                s0 = fmaf(w0[ky * 3 + kx], v, s0);
                s1 = fmaf(w1[ky * 3 + kx], v, s1);
                s2 = fmaf(w2[ky * 3 + kx], v, s2);
            }
        }
        float* p = &sc[r * 100 + c * 3];
        p[0] = s0; p[1] = s1; p[2] = s2;
    }
    __syncthreads();

    const int i = i0 + ty, j = j0 + tx;
    if (i >= Hh || j >= Wh) return;

    const float* r0 = &sc[(2 * ty + 0) * 100 + (2 * tx) * 3];
    const float* r1 = &sc[(2 * ty + 1) * 100 + (2 * tx) * 3];
    const float* r2 = &sc[(2 * ty + 2) * 100 + (2 * tx) * 3];
#define MAX3_(a, bq, cq) fmaxf(fmaxf((a), (bq)), (cq))
    float m0 = MAX3_(MAX3_(r0[0], r0[3], r0[6]), MAX3_(r1[0], r1[3], r1[6]), MAX3_(r2[0], r2[3], r2[6]));
    float m1 = MAX3_(MAX3_(r0[1], r0[4], r0[7]), MAX3_(r1[1], r1[4], r1[7]), MAX3_(r2[1], r2[4], r2[7]));
    float m2 = MAX3_(MAX3_(r0[2], r0[5], r0[8]), MAX3_(r1[2], r1[5], r1[8]), MAX3_(r2[2], r2[5], r2[8]));
    m0 = fmaxf(m0, 0.f); m1 = fmaxf(m1, 0.f); m2 = fmaxf(m2, 0.f);   // relu commutes with max

    uint2 v;
    v.x = h2u(__floats2half2_rn(m0, m1));                       // (c0,c1) f16 pair
    v.y = (unsigned int)__half_as_ushort(__float2half_rn(m2));  // (c2, 0)
    hp[(b * HP + i + 2) * HP + (j + 2)] = v;
}

// ---------------- Kernel B: f16 MFMA offset-conv(+bias col) + LDS-tiled bilinear gather + einsum ----------------
// R9 structure (3 barriers, single shared B, int clamps) + ONE change: h rows [y, y+4] staged in
// LDS (10.4 KB, contiguous copy); gather taps hit the tile via wave-uniform __all check, with the
// exact R9 global path as fallback. LDS: A[0,16384) + B[16384,18432) + tile[18432,28792);
// om overlays [0,17408) after MFMA.
__global__ __launch_bounds__(256, 5) void dcn_kernel(
    const uint2* __restrict__ hp,      // [B][259][259] 4xf16
    const float* __restrict__ off_w,   // [27,27]
    const float* __restrict__ off_b,   // [27]
    const float* __restrict__ dcn_w,   // [3,3,9]
    const float* __restrict__ dcn_b,   // [3]
    float* __restrict__ out)           // [B,3,255,255]
{
    __shared__ __align__(16) char smem[28800];

    const int y   = blockIdx.x;
    const int b   = blockIdx.y;
    const int tid = threadIdx.x;
    const int x   = tid;

    const uint2* hb = hp + b * (HP * HP);

    // ---- h tile fill: padded rows [y, y+4] = 1295 contiguous uint2 (y<=254 -> max idx 67080 < 259^2)
    {
        uint2* tile = (uint2*)(smem + 18432);
        const uint2* src = hb + (unsigned)y * HP;
        for (int t = tid; t < 1295; t += 256) tile[t] = src[t];
    }

    // ---- B matrix -> LDS (32x32 f16): cols 0..26 = off_w, col 27 = off_b (bias), rest 0
    {
        unsigned short* Bm = (unsigned short*)(smem + 16384);
        for (int idx = tid; idx < 1024; idx += 256) {
            int n = idx >> 5, k = idx & 31;
            float v = 0.f;
            if (n < 27) { if (k < 27) v = off_w[n * 27 + k]; else if (k == 27) v = off_b[n]; }
            Bm[n * 32 + k] = __half_as_ushort(__float2half_rn(v));
        }
    }

    // ---- im2col row for pixel x from padded h (2 loads per row: dwordx4 + dwordx2)
    unsigned int L[9], Hv[9];
#pragma unroll
    for (int ky = 0; ky < 3; ++ky) {
        const unsigned int rbase = (unsigned int)(y + 1 + ky) * HP + (unsigned int)(x + 1);
        u32x4 r01;                                  // kx=0,1
        __builtin_memcpy(&r01, hb + rbase, 16);
        uint2 r2 = hb[rbase + 2];                   // kx=2
        L[ky * 3 + 0]  = r01.x;  Hv[ky * 3 + 0] = r01.y;
        L[ky * 3 + 1]  = r01.z;  Hv[ky * 3 + 1] = r01.w;
        L[ky * 3 + 2]  = r2.x;   Hv[ky * 3 + 2] = r2.y;
    }

    // ---- assemble A row (k=c*9+p; k=27 -> constant f16(1.0) bias column)
    {
        unsigned int T[16];
        T[0]  = (L[0] & 0xFFFFu) | (L[1] << 16);
        T[1]  = (L[2] & 0xFFFFu) | (L[3] << 16);
        T[2]  = (L[4] & 0xFFFFu) | (L[5] << 16);
        T[3]  = (L[6] & 0xFFFFu) | (L[7] << 16);
        T[4]  = (L[8] & 0xFFFFu) | (L[0] & 0xFFFF0000u);
        T[5]  = (L[1] >> 16) | (L[2] & 0xFFFF0000u);
        T[6]  = (L[3] >> 16) | (L[4] & 0xFFFF0000u);
        T[7]  = (L[5] >> 16) | (L[6] & 0xFFFF0000u);
        T[8]  = (L[7] >> 16) | (L[8] & 0xFFFF0000u);
        T[9]  = (Hv[0] & 0xFFFFu) | (Hv[1] << 16);
        T[10] = (Hv[2] & 0xFFFFu) | (Hv[3] << 16);
        T[11] = (Hv[4] & 0xFFFFu) | (Hv[5] << 16);
        T[12] = (Hv[6] & 0xFFFFu) | (Hv[7] << 16);
        T[13] = (Hv[8] & 0xFFFFu) | 0x3C000000u;   // f16(1.0) in k=27 slot
        T[14] = 0u;
        T[15] = 0u;
#pragma unroll
        for (int c4 = 0; c4 < 4; ++c4) {
            u32x4 v = { T[c4 * 4 + 0], T[c4 * 4 + 1], T[c4 * 4 + 2], T[c4 * 4 + 3] };
            *(u32x4*)(smem + (c4 * 256 + tid) * 16) = v;
        }
    }
    __syncthreads();

    // ---- MFMA (swapped operands): D = off_w x im2col^T = om^T
    {
        const int wave = tid >> 6, lane = tid & 63;
        const int lrow = lane & 15, lchunk = lane >> 4;
        const _Float16* As = (const _Float16*)smem;
        const _Float16* Bs = (const _Float16*)(smem + 16384);

        f16x8 afr[4];
#pragma unroll
        for (int m = 0; m < 4; ++m)
            afr[m] = *(const f16x8*)(As + (lchunk * 256 + wave * 64 + m * 16 + lrow) * 8);
        f16x8 bfr[2];
#pragma unroll
        for (int nt = 0; nt < 2; ++nt)
            bfr[nt] = *(const f16x8*)(Bs + ((nt * 16 + lrow) * 32 + lchunk * 8));

        f32x4 acc[4][2];
#pragma unroll
        for (int m = 0; m < 4; ++m)
#pragma unroll
            for (int nt = 0; nt < 2; ++nt) {
                f32x4 z = {0.f, 0.f, 0.f, 0.f};
                acc[m][nt] = __builtin_amdgcn_mfma_f32_16x16x32_f16(bfr[nt], afr[m], z, 0, 0, 0);
            }
        __syncthreads();   // A/B reads done before om overlays (om spans [0,17408))

        // om f16 px-major: byte = px*68 + n*2; lane writes 4 consecutive n for one px.
#pragma unroll
        for (int m = 0; m < 4; ++m)
#pragma unroll
            for (int nt = 0; nt < 2; ++nt) {
                const int n0  = nt * 16 + lchunk * 4;
                const int pxw = wave * 64 + m * 16 + lrow;
                unsigned int p0 = h2u(__floats2half2_rn(acc[m][nt][0], acc[m][nt][1]));
                unsigned int p1 = h2u(__floats2half2_rn(acc[m][nt][2], acc[m][nt][3]));
                unsigned int* q = (unsigned int*)(smem + pxw * 68 + n0 * 2);
                q[0] = p0;
                q[1] = p1;
            }
    }
    __syncthreads();

    // ---- gather + mask + einsum; om row for pixel x: 14 conflict-free ds_read_b32
    unsigned int o2[14];
    {
        const unsigned int* omp = (const unsigned int*)(smem + x * 68);
#pragma unroll
        for (int j = 0; j < 14; ++j) o2[j] = omp[j];
    }
#define OM_(n) (((n) & 1) ? __high2float(u2h2(o2[(n) >> 1])) : __low2float(u2h2(o2[(n) >> 1])))

    float outv0 = dcn_b[0], outv1 = dcn_b[1], outv2 = dcn_b[2];
    const float yf = (float)y, xf = (float)x;
    const uint2* tile = (const uint2*)(smem + 18432);

#pragma unroll
    for (int k = 0; k < 9; ++k) {
        const float dy  = OM_(k);
        const float dxx = OM_(9 + k);
        const float zm  = OM_(18 + k);
        const float msk = __builtin_amdgcn_rcpf(1.f + __expf(-zm));

        const float py = yf + (float)(k / 3 - 1) + dy;
        const float px = xf + (float)(k % 3 - 1) + dxx;

        const float y0f = floorf(py), x0f = floorf(px);
        const float ly = py - y0f, lx = px - x0f;
        int iy = (int)y0f + 2, ix = (int)x0f + 2;
        iy = min(max(iy, 0), 257);           // out-of-range corners land on stored zeros
        ix = min(max(ix, 0), 257);

        u32x4 ua, ub;                         // {AA.x, AA.y, AB.x, AB.y}, {BA.., BB..}
        const int tr = iy - y;                // tile row; rows [y, y+4] staged, need tr in [0,3]
        if (__all((unsigned)tr <= 3u)) {      // wave-uniform fast path (~always taken)
            const uint2* tp = tile + tr * 259 + ix;   // ix<=257 -> ix+1<=258 in-tile
            __builtin_memcpy(&ua, tp, 16);
            __builtin_memcpy(&ub, tp + 259, 16);
        } else {                              // exact R9 global path (outliers)
            const unsigned int idx = (unsigned int)iy * HP + (unsigned int)ix;
            __builtin_memcpy(&ua, hb + idx, 16);
            __builtin_memcpy(&ub, hb + idx + HP, 16);
        }

        const float my1 = ly * msk;
        const float my0 = msk - my1;          // (1-ly)*msk
        const float lx1 = 1.f - lx;
        const float w00 = my0 * lx1, w01 = my0 * lx;
        const float w10 = my1 * lx1, w11 = my1 * lx;

        // packed-f16 blend: .x/.z lanes hold (c0,c1); .y/.w hold (c2,0)
        const __half2 W00 = __float2half2_rn(w00);
        const __half2 W01 = __float2half2_rn(w01);
        const __half2 W10 = __float2half2_rn(w10);
        const __half2 W11 = __float2half2_rn(w11);
        __half2 sA = __hmul2(W00, u2h2(ua.x));
        sA = __hfma2(W01, u2h2(ua.z), sA);
        sA = __hfma2(W10, u2h2(ub.x), sA);
        sA = __hfma2(W11, u2h2(ub.z), sA);
        __half2 sB = __hmul2(W00, u2h2(ua.y));
        sB = __hfma2(W01, u2h2(ua.w), sB);
        sB = __hfma2(W10, u2h2(ub.y), sB);
        sB = __hfma2(W11, u2h2(ub.w), sB);
        const float s0 = __low2float(sA);
        const float s1 = __high2float(sA);
        const float s2 = __low2float(sB);

        outv0 = fmaf(dcn_w[0 * 27 + 0 * 9 + k], s0, outv0);
        outv0 = fmaf(dcn_w[0 * 27 + 1 * 9 + k], s1, outv0);
        outv0 = fmaf(dcn_w[0 * 27 + 2 * 9 + k], s2, outv0);
        outv1 = fmaf(dcn_w[1 * 27 + 0 * 9 + k], s0, outv1);
        outv1 = fmaf(dcn_w[1 * 27 + 1 * 9 + k], s1, outv1);
        outv1 = fmaf(dcn_w[1 * 27 + 2 * 9 + k], s2, outv1);
        outv2 = fmaf(dcn_w[2 * 27 + 0 * 9 + k], s0, outv2);
        outv2 = fmaf(dcn_w[2 * 27 + 1 * 9 + k], s1, outv2);
        outv2 = fmaf(dcn_w[2 * 27 + 2 * 9 + k], s2, outv2);
    }

    if (x < Wh) {
        const int hwsz = Hh * Wh;
        const int o = (b * 3) * hwsz + y * Wh + x;
        out[o]            = outv0;
        out[o + hwsz]     = outv1;
        out[o + 2 * hwsz] = outv2;
    }
}

extern "C" void kernel_launch(void* const* d_in, const int* in_sizes, int n_in,
                              void* d_out, int out_size, void* d_ws, size_t ws_size,
                              hipStream_t stream) {
    const float* x       = (const float*)d_in[0];
    const float* conv1_w = (const float*)d_in[1];
    const float* conv1_b = (const float*)d_in[2];
    const float* off_w   = (const float*)d_in[3];
    const float* off_b   = (const float*)d_in[4];
    const float* dcn_w   = (const float*)d_in[5];
    const float* dcn_b   = (const float*)d_in[6];
    float* out = (float*)d_out;
    uint2* hp  = (uint2*)d_ws;    // 32*259*259*8 B = 17.2 MiB

    conv_pool_kernel<<<dim3(16, 17, B_), dim3(16, 16), 0, stream>>>(x, conv1_w, conv1_b, hp);
    dcn_kernel<<<dim3(Hh, B_), 256, 0, stream>>>(hp, off_w, off_b, dcn_w, dcn_b, out);
}

// Round 13
// 67.122 us; speedup vs baseline: 1.8410x; 1.8410x over previous
//
#include <hip/hip_runtime.h>
#include <hip/hip_fp16.h>
#include <math.h>

#define B_  32
#define H0  512
#define W0  512
#define Hh  255
#define Wh  255
#define HP  259   // padded: rows/cols 0,1 zero; 2..256 = data y=0..254; 257,258 zero

typedef __attribute__((ext_vector_type(8))) _Float16 f16x8;
typedef __attribute__((ext_vector_type(4))) float    f32x4;
typedef __attribute__((ext_vector_type(4))) unsigned int u32x4;

static __device__ __forceinline__ __half2 u2h2(unsigned int u) {
    __half2 h; __builtin_memcpy(&h, &u, 4); return h;
}
static __device__ __forceinline__ unsigned int h2u(__half2 h) {
    unsigned int u; __builtin_memcpy(&u, &h, 4); return u;
}

// ---------------- Kernel A: conv1+ReLU+maxpool -> padded f16x4 h; ring blocks zero the pad ----------------
// (R9-proven version, byte-identical)
__global__ __launch_bounds__(256) void conv_pool_kernel(
    const float* __restrict__ x,      // [B,1,512,512]
    const float* __restrict__ w,      // [3,1,3,3]
    const float* __restrict__ bias,   // [3]
    uint2* __restrict__ hp)           // [B][259][259] of 4xf16 (c0,c1,c2,0)
{
    const int b = blockIdx.z;
    const int tx = threadIdx.x, ty = threadIdx.y;
    const int tid = ty * 16 + tx;

    if (blockIdx.y == 16) {           // ---- pad-ring zeroing (16 blocks/image) ----
        uint2* hpb = hp + b * (HP * HP);
        const int gid = blockIdx.x * 256 + tid;
        if (gid < 2072) {
            int r, c;
            if (gid < 1036) {                      // row strips 0,1,257,258
                int rr = gid / 259; c = gid - rr * 259;
                r = rr + (rr >= 2 ? 255 : 0);
            } else {                               // col strips 0,1,257,258
                int u = gid - 1036;
                int cc = u / 259; r = u - cc * 259;
                c = cc + (cc >= 2 ? 255 : 0);
            }
            hpb[r * HP + c] = make_uint2(0u, 0u);
        }
        return;
    }

    __shared__ float sx[35][36];
    __shared__ float sc[33 * 100];    // conv values [r][c*3+ch]; lane stride 6 dwords -> conflict-free
    const int i0 = blockIdx.y * 16;
    const int j0 = blockIdx.x * 16;

    const float* xb = x + b * (H0 * W0);
    for (int t = tid; t < 35 * 35; t += 256) {
        int r = t / 35, c = t - r * 35;
        int gr = 2 * i0 - 1 + r;
        int gc = 2 * j0 - 1 + c;
        float v = 0.f;
        if ((unsigned)gr < (unsigned)H0 && (unsigned)gc < (unsigned)W0) v = xb[gr * W0 + gc];
        sx[r][c] = v;
    }
    __syncthreads();

    float w0[9], w1[9], w2[9];
#pragma unroll
    for (int t = 0; t < 9; ++t) { w0[t] = w[t]; w1[t] = w[9 + t]; w2[t] = w[18 + t]; }
    const float b0 = bias[0], b1 = bias[1], b2 = bias[2];

    for (int t = tid; t < 33 * 33; t += 256) {
        int r = t / 33, c = t - r * 33;
        float s0 = b0, s1 = b1, s2 = b2;
#pragma unroll
        for (int ky = 0; ky < 3; ++ky) {
#pragma unroll
            for (int kx = 0; kx < 3; ++kx) {
                float v = sx[r + ky][c + kx];
                s0 = fmaf(w0[ky * 3 + kx], v, s0);
                s1 = fmaf(w1[ky * 3 + kx], v, s1);
                s2 = fmaf(w2[ky * 3 + kx], v, s2);
            }
        }
        float* p = &sc[r * 100 + c * 3];
        p[0] = s0; p[1] = s1; p[2] = s2;
    }
    __syncthreads();

    const int i = i0 + ty, j = j0 + tx;
    if (i >= Hh || j >= Wh) return;

    const float* r0 = &sc[(2 * ty + 0) * 100 + (2 * tx) * 3];
    const float* r1 = &sc[(2 * ty + 1) * 100 + (2 * tx) * 3];
    const float* r2 = &sc[(2 * ty + 2) * 100 + (2 * tx) * 3];
#define MAX3_(a, bq, cq) fmaxf(fmaxf((a), (bq)), (cq))
    float m0 = MAX3_(MAX3_(r0[0], r0[3], r0[6]), MAX3_(r1[0], r1[3], r1[6]), MAX3_(r2[0], r2[3], r2[6]));
    float m1 = MAX3_(MAX3_(r0[1], r0[4], r0[7]), MAX3_(r1[1], r1[4], r1[7]), MAX3_(r2[1], r2[4], r2[7]));
    float m2 = MAX3_(MAX3_(r0[2], r0[5], r0[8]), MAX3_(r1[2], r1[5], r1[8]), MAX3_(r2[2], r2[5], r2[8]));
    m0 = fmaxf(m0, 0.f); m1 = fmaxf(m1, 0.f); m2 = fmaxf(m2, 0.f);   // relu commutes with max

    uint2 v;
    v.x = h2u(__floats2half2_rn(m0, m1));                       // (c0,c1) f16 pair
    v.y = (unsigned int)__half_as_ushort(__float2half_rn(m2));  // (c2, 0)
    hp[(b * HP + i + 2) * HP + (j + 2)] = v;
}

// ---------------- Kernel B: f16 MFMA offset-conv(+bias col) + padded bilinear gather + einsum ----------------
// R9-proven structure (LDS 18432, 3 barriers, shared B, global gather). ONE change vs R9:
// float-domain clamp med3(py,-2,255) replaces the 4 int clamps per tap (pad ring absorbs
// clamped corners with identical semantics -- see analysis).
__global__ __launch_bounds__(256, 5) void dcn_kernel(
    const uint2* __restrict__ hp,      // [B][259][259] 4xf16
    const float* __restrict__ off_w,   // [27,27]
    const float* __restrict__ off_b,   // [27]
    const float* __restrict__ dcn_w,   // [3,3,9]
    const float* __restrict__ dcn_b,   // [3]
    float* __restrict__ out)           // [B,3,255,255]
{
    __shared__ __align__(16) char smem[18432];

    const int y   = blockIdx.x;
    const int b   = blockIdx.y;
    const int tid = threadIdx.x;
    const int x   = tid;

    const uint2* hb = hp + b * (HP * HP);

    // ---- B matrix -> LDS (32x32 f16): cols 0..26 = off_w, col 27 = off_b (bias), rest 0
    {
        unsigned short* Bm = (unsigned short*)(smem + 16384);
        for (int idx = tid; idx < 1024; idx += 256) {
            int n = idx >> 5, k = idx & 31;
            float v = 0.f;
            if (n < 27) { if (k < 27) v = off_w[n * 27 + k]; else if (k == 27) v = off_b[n]; }
            Bm[n * 32 + k] = __half_as_ushort(__float2half_rn(v));
        }
    }

    // ---- im2col row for pixel x from padded h (2 loads per row: dwordx4 + dwordx2)
    unsigned int L[9], Hv[9];
#pragma unroll
    for (int ky = 0; ky < 3; ++ky) {
        const unsigned int rbase = (unsigned int)(y + 1 + ky) * HP + (unsigned int)(x + 1);
        u32x4 r01;                                  // kx=0,1
        __builtin_memcpy(&r01, hb + rbase, 16);
        uint2 r2 = hb[rbase + 2];                   // kx=2
        L[ky * 3 + 0]  = r01.x;  Hv[ky * 3 + 0] = r01.y;
        L[ky * 3 + 1]  = r01.z;  Hv[ky * 3 + 1] = r01.w;
        L[ky * 3 + 2]  = r2.x;   Hv[ky * 3 + 2] = r2.y;
    }

    // ---- assemble A row (k=c*9+p; k=27 -> constant f16(1.0) bias column)
    {
        unsigned int T[16];
        T[0]  = (L[0] & 0xFFFFu) | (L[1] << 16);
        T[1]  = (L[2] & 0xFFFFu) | (L[3] << 16);
        T[2]  = (L[4] & 0xFFFFu) | (L[5] << 16);
        T[3]  = (L[6] & 0xFFFFu) | (L[7] << 16);
        T[4]  = (L[8] & 0xFFFFu) | (L[0] & 0xFFFF0000u);
        T[5]  = (L[1] >> 16) | (L[2] & 0xFFFF0000u);
        T[6]  = (L[3] >> 16) | (L[4] & 0xFFFF0000u);
        T[7]  = (L[5] >> 16) | (L[6] & 0xFFFF0000u);
        T[8]  = (L[7] >> 16) | (L[8] & 0xFFFF0000u);
        T[9]  = (Hv[0] & 0xFFFFu) | (Hv[1] << 16);
        T[10] = (Hv[2] & 0xFFFFu) | (Hv[3] << 16);
        T[11] = (Hv[4] & 0xFFFFu) | (Hv[5] << 16);
        T[12] = (Hv[6] & 0xFFFFu) | (Hv[7] << 16);
        T[13] = (Hv[8] & 0xFFFFu) | 0x3C000000u;   // f16(1.0) in k=27 slot
        T[14] = 0u;
        T[15] = 0u;
#pragma unroll
        for (int c4 = 0; c4 < 4; ++c4) {
            u32x4 v = { T[c4 * 4 + 0], T[c4 * 4 + 1], T[c4 * 4 + 2], T[c4 * 4 + 3] };
            *(u32x4*)(smem + (c4 * 256 + tid) * 16) = v;
        }
    }
    __syncthreads();

    // ---- MFMA (swapped operands): D = off_w x im2col^T = om^T
    {
        const int wave = tid >> 6, lane = tid & 63;
        const int lrow = lane & 15, lchunk = lane >> 4;
        const _Float16* As = (const _Float16*)smem;
        const _Float16* Bs = (const _Float16*)(smem + 16384);

        f16x8 afr[4];
#pragma unroll
        for (int m = 0; m < 4; ++m)
            afr[m] = *(const f16x8*)(As + (lchunk * 256 + wave * 64 + m * 16 + lrow) * 8);
        f16x8 bfr[2];
#pragma unroll
        for (int nt = 0; nt < 2; ++nt)
            bfr[nt] = *(const f16x8*)(Bs + ((nt * 16 + lrow) * 32 + lchunk * 8));

        f32x4 acc[4][2];
#pragma unroll
        for (int m = 0; m < 4; ++m)
#pragma unroll
            for (int nt = 0; nt < 2; ++nt) {
                f32x4 z = {0.f, 0.f, 0.f, 0.f};
                acc[m][nt] = __builtin_amdgcn_mfma_f32_16x16x32_f16(bfr[nt], afr[m], z, 0, 0, 0);
            }
        __syncthreads();   // A/B reads done before om overlays (om spans [0,17408))

        // om f16 px-major: byte = px*68 + n*2; lane writes 4 consecutive n for one px.
#pragma unroll
        for (int m = 0; m < 4; ++m)
#pragma unroll
            for (int nt = 0; nt < 2; ++nt) {
                const int n0  = nt * 16 + lchunk * 4;
                const int pxw = wave * 64 + m * 16 + lrow;
                unsigned int p0 = h2u(__floats2half2_rn(acc[m][nt][0], acc[m][nt][1]));
                unsigned int p1 = h2u(__floats2half2_rn(acc[m][nt][2], acc[m][nt][3]));
                unsigned int* q = (unsigned int*)(smem + pxw * 68 + n0 * 2);
                q[0] = p0;
                q[1] = p1;
            }
    }
    __syncthreads();

    // ---- gather + mask + einsum; om row for pixel x: 14 conflict-free ds_read_b32
    unsigned int o2[14];
    {
        const unsigned int* omp = (const unsigned int*)(smem + x * 68);
#pragma unroll
        for (int j = 0; j < 14; ++j) o2[j] = omp[j];
    }
#define OM_(n) (((n) & 1) ? __high2float(u2h2(o2[(n) >> 1])) : __low2float(u2h2(o2[(n) >> 1])))

    float outv0 = dcn_b[0], outv1 = dcn_b[1], outv2 = dcn_b[2];
    const float yf = (float)y, xf = (float)x;

#pragma unroll
    for (int k = 0; k < 9; ++k) {
        const float dy  = OM_(k);
        const float dxx = OM_(9 + k);
        const float zm  = OM_(18 + k);
        const float msk = __builtin_amdgcn_rcpf(1.f + __expf(-zm));

        // float-domain clamp to [-2,255] (v_med3_f32): clamped corners land on the stored
        // zero ring, matching reference validity masking. ly/lx from the clamped coord.
        const float py = fminf(fmaxf(yf + (float)(k / 3 - 1) + dy,  -2.f), 255.f);
        const float px = fminf(fmaxf(xf + (float)(k % 3 - 1) + dxx, -2.f), 255.f);

        const float y0f = floorf(py), x0f = floorf(px);
        const float ly = py - y0f, lx = px - x0f;
        const int iy = (int)y0f + 2;          // in [0,257]
        const int ix = (int)x0f + 2;

        const unsigned int idx = (unsigned int)iy * HP + (unsigned int)ix;
        u32x4 ua, ub;                         // {AA.x, AA.y, AB.x, AB.y}, {BA.., BB..}
        __builtin_memcpy(&ua, hb + idx, 16);
        __builtin_memcpy(&ub, hb + idx + HP, 16);

        const float my1 = ly * msk;
        const float my0 = msk - my1;          // (1-ly)*msk
        const float lx1 = 1.f - lx;
        const float w00 = my0 * lx1, w01 = my0 * lx;
        const float w10 = my1 * lx1, w11 = my1 * lx;

        // packed-f16 blend: .x/.z lanes hold (c0,c1); .y/.w hold (c2,0)
        const __half2 W00 = __float2half2_rn(w00);
        const __half2 W01 = __float2half2_rn(w01);
        const __half2 W10 = __float2half2_rn(w10);
        const __half2 W11 = __float2half2_rn(w11);
        __half2 sA = __hmul2(W00, u2h2(ua.x));
        sA = __hfma2(W01, u2h2(ua.z), sA);
        sA = __hfma2(W10, u2h2(ub.x), sA);
        sA = __hfma2(W11, u2h2(ub.z), sA);
        __half2 sB = __hmul2(W00, u2h2(ua.y));
        sB = __hfma2(W01, u2h2(ua.w), sB);
        sB = __hfma2(W10, u2h2(ub.y), sB);
        sB = __hfma2(W11, u2h2(ub.w), sB);
        const float s0 = __low2float(sA);
        const float s1 = __high2float(sA);
        const float s2 = __low2float(sB);

        outv0 = fmaf(dcn_w[0 * 27 + 0 * 9 + k], s0, outv0);
        outv0 = fmaf(dcn_w[0 * 27 + 1 * 9 + k], s1, outv0);
        outv0 = fmaf(dcn_w[0 * 27 + 2 * 9 + k], s2, outv0);
        outv1 = fmaf(dcn_w[1 * 27 + 0 * 9 + k], s0, outv1);
        outv1 = fmaf(dcn_w[1 * 27 + 1 * 9 + k], s1, outv1);
        outv1 = fmaf(dcn_w[1 * 27 + 2 * 9 + k], s2, outv1);
        outv2 = fmaf(dcn_w[2 * 27 + 0 * 9 + k], s0, outv2);
        outv2 = fmaf(dcn_w[2 * 27 + 1 * 9 + k], s1, outv2);
        outv2 = fmaf(dcn_w[2 * 27 + 2 * 9 + k], s2, outv2);
    }

    if (x < Wh) {
        const int hwsz = Hh * Wh;
        const int o = (b * 3) * hwsz + y * Wh + x;
        out[o]            = outv0;
        out[o + hwsz]     = outv1;
        out[o + 2 * hwsz] = outv2;
    }
}

extern "C" void kernel_launch(void* const* d_in, const int* in_sizes, int n_in,
                              void* d_out, int out_size, void* d_ws, size_t ws_size,
                              hipStream_t stream) {
    const float* x       = (const float*)d_in[0];
    const float* conv1_w = (const float*)d_in[1];
    const float* conv1_b = (const float*)d_in[2];
    const float* off_w   = (const float*)d_in[3];
    const float* off_b   = (const float*)d_in[4];
    const float* dcn_w   = (const float*)d_in[5];
    const float* dcn_b   = (const float*)d_in[6];
    float* out = (float*)d_out;
    uint2* hp  = (uint2*)d_ws;    // 32*259*259*8 B = 17.2 MiB

    conv_pool_kernel<<<dim3(16, 17, B_), dim3(16, 16), 0, stream>>>(x, conv1_w, conv1_b, hp);
    dcn_kernel<<<dim3(Hh, B_), 256, 0, stream>>>(hp, off_w, off_b, dcn_w, dcn_b, out);
}